// Round 1
// baseline (813.299 us; speedup 1.0000x reference)
//
#include <hip/hip_runtime.h>

// ---------------------------------------------------------------------------
// SelfAttention: B=1024, C=N=256.  Per batch:
//   Q=WqX+bq; K=WkX+bk; V=WvX+bv; S=Q K^T /16; P=softmax_rows(S); O=V P;
//   out = gamma*O + x
// Identity used to avoid materializing K:
//   S = (Q X^T) Wk^T + qsum ⊗ bk,   qsum[c] = sum_n Q[c,n]
// ---------------------------------------------------------------------------

typedef __attribute__((ext_vector_type(8))) short bf16x8;
typedef __attribute__((ext_vector_type(4))) short bf16x4;
typedef __attribute__((ext_vector_type(4))) float f32x4;

#define MFMA16(a, b, c) __builtin_amdgcn_mfma_f32_16x16x32_bf16((a), (b), (c), 0, 0, 0)

static __device__ __forceinline__ unsigned short f2bf(float f) {
  unsigned int u = __float_as_uint(f);
  u += 0x7fffu + ((u >> 16) & 1u);   // round-to-nearest-even
  return (unsigned short)(u >> 16);
}

static __device__ __forceinline__ bf16x8 cvt8(const float* __restrict__ p) {
  const float4* q = (const float4*)p;
  float4 a = q[0], b = q[1];
  bf16x8 r;
  r[0] = (short)f2bf(a.x); r[1] = (short)f2bf(a.y);
  r[2] = (short)f2bf(a.z); r[3] = (short)f2bf(a.w);
  r[4] = (short)f2bf(b.x); r[5] = (short)f2bf(b.y);
  r[6] = (short)f2bf(b.z); r[7] = (short)f2bf(b.w);
  return r;
}

// 256 rows x 512B swizzled LDS buffer; XOR spreads stride-512B row accesses
// across 8 distinct 16B slots (G4 fix for the 16-way conflict).
static __device__ __forceinline__ int swz(int row, int byteInRow) {
  return row * 512 + (byteInRow ^ ((row & 7) << 4));
}

// ---------------------------------------------------------------------------
// Kernel 1: Xt[b][n][i] = bf16(x[b][i][n])   (B-fragment source for W*X GEMMs)
// ---------------------------------------------------------------------------
__global__ void k_transpose(const float* __restrict__ x, unsigned short* __restrict__ xt) {
  __shared__ float tile[64][65];
  const int b = blockIdx.x;
  const float* xb = x + (size_t)b * 65536;
  unsigned short* xtb = xt + (size_t)b * 65536;
  const int t = threadIdx.x, tx = t & 63, ty = t >> 6;
  for (int tb = 0; tb < 16; ++tb) {
    const int c0 = (tb >> 2) * 64, n0 = (tb & 3) * 64;
    __syncthreads();
#pragma unroll
    for (int yy = 0; yy < 16; ++yy) {
      const int r = ty + yy * 4;
      tile[r][tx] = xb[(c0 + r) * 256 + n0 + tx];
    }
    __syncthreads();
#pragma unroll
    for (int yy = 0; yy < 16; ++yy) {
      const int r = ty + yy * 4;
      xtb[(n0 + r) * 256 + c0 + tx] = f2bf(tile[tx][r]);
    }
  }
}

// ---------------------------------------------------------------------------
// Kernel 2: V[b] = Wv x[b] + bv  -> ws, bf16 row-major [c][n]
// 8 waves, each a 64x128 tile; LDS repack for coalesced 16B stores.
// ---------------------------------------------------------------------------
__global__ __launch_bounds__(512, 2) void k_v(const float* __restrict__ Wv,
                                              const float* __restrict__ bv,
                                              const unsigned short* __restrict__ xt,
                                              unsigned short* __restrict__ vout) {
  extern __shared__ char smem[];
  const int b = blockIdx.x;
  const int tid = threadIdx.x, w = tid >> 6, lane = tid & 63, lo = lane & 15, hi = lane >> 4;
  const unsigned short* xtb = xt + (size_t)b * 65536;
  const int r0 = (w >> 1) * 64, c0 = (w & 1) * 128;

  f32x4 acc[4][8];
#pragma unroll
  for (int i = 0; i < 4; ++i)
#pragma unroll
    for (int j = 0; j < 8; ++j) acc[i][j] = (f32x4){0.f, 0.f, 0.f, 0.f};

  for (int k0 = 0; k0 < 256; k0 += 32) {
    bf16x8 a[4];
#pragma unroll
    for (int rt = 0; rt < 4; ++rt) a[rt] = cvt8(Wv + (r0 + rt * 16 + lo) * 256 + k0 + hi * 8);
#pragma unroll
    for (int ct = 0; ct < 8; ++ct) {
      bf16x8 bb = *(const bf16x8*)(xtb + (c0 + ct * 16 + lo) * 256 + k0 + hi * 8);
#pragma unroll
      for (int rt = 0; rt < 4; ++rt) acc[rt][ct] = MFMA16(a[rt], bb, acc[rt][ct]);
    }
  }
#pragma unroll
  for (int rt = 0; rt < 4; ++rt)
#pragma unroll
    for (int reg = 0; reg < 4; ++reg) {
      const int c = r0 + rt * 16 + hi * 4 + reg;
      const float bvc = bv[c];
#pragma unroll
      for (int ct = 0; ct < 8; ++ct) {
        const int n = c0 + ct * 16 + lo;
        *(unsigned short*)(smem + c * 512 + n * 2) = f2bf(acc[rt][ct][reg] + bvc);
      }
    }
  __syncthreads();
  char* vb = (char*)(vout + (size_t)b * 65536);
#pragma unroll
  for (int i = 0; i < 16; ++i) {
    const int off = (i * 512 + tid) * 16;
    *(int4*)(vb + off) = *(const int4*)(smem + off);
  }
}

// ---------------------------------------------------------------------------
// Kernel 3: fused attention per batch.
// One 256x512B swizzled LDS buffer reused: Q -> R=(Q X^T)^T-store -> P^T
// ---------------------------------------------------------------------------
__global__ __launch_bounds__(512, 2) void attn_fused(
    const float* __restrict__ x, const float* __restrict__ Wq, const float* __restrict__ bq,
    const float* __restrict__ Wk, const float* __restrict__ bk, const float* __restrict__ gamma,
    const unsigned short* __restrict__ Xt, const unsigned short* __restrict__ V,
    float* __restrict__ out) {
  extern __shared__ char smem[];
  float* qsum = (float*)(smem + 131072);
  const int b = blockIdx.x;
  const int tid = threadIdx.x, w = tid >> 6, lane = tid & 63, lo = lane & 15, hi = lane >> 4;
  const float* xb = x + (size_t)b * 65536;
  const unsigned short* xtb = Xt + (size_t)b * 65536;
  const unsigned short* vbp = V + (size_t)b * 65536;
  const int wr = w >> 1, wc = w & 1;

  if (tid < 256) qsum[tid] = 0.f;
  __syncthreads();

  // ---- Phase 1: Q = Wq*X + bq -> LDS (swizzled [c][n]); qsum[c] ----
  {
    const int r0 = wr * 64, c0 = wc * 128;
    f32x4 acc[4][8];
#pragma unroll
    for (int i = 0; i < 4; ++i)
#pragma unroll
      for (int j = 0; j < 8; ++j) acc[i][j] = (f32x4){0.f, 0.f, 0.f, 0.f};
    for (int k0 = 0; k0 < 256; k0 += 32) {
      bf16x8 a[4];
#pragma unroll
      for (int rt = 0; rt < 4; ++rt) a[rt] = cvt8(Wq + (r0 + rt * 16 + lo) * 256 + k0 + hi * 8);
#pragma unroll
      for (int ct = 0; ct < 8; ++ct) {
        bf16x8 bb = *(const bf16x8*)(xtb + (c0 + ct * 16 + lo) * 256 + k0 + hi * 8);
#pragma unroll
        for (int rt = 0; rt < 4; ++rt) acc[rt][ct] = MFMA16(a[rt], bb, acc[rt][ct]);
      }
    }
#pragma unroll
    for (int rt = 0; rt < 4; ++rt)
#pragma unroll
      for (int reg = 0; reg < 4; ++reg) {
        const int c = r0 + rt * 16 + hi * 4 + reg;
        const float bqc = bq[c];
        float part = 0.f;
#pragma unroll
        for (int ct = 0; ct < 8; ++ct) {
          const float v = acc[rt][ct][reg] + bqc;
          part += v;
          const int n = c0 + ct * 16 + lo;
          *(unsigned short*)(smem + swz(c, n * 2)) = f2bf(v);
        }
        part += __shfl_xor(part, 1);
        part += __shfl_xor(part, 2);
        part += __shfl_xor(part, 4);
        part += __shfl_xor(part, 8);
        if (lo == 0) atomicAdd(&qsum[c], part);
      }
  }
  __syncthreads();

  // ---- Phase 2: R^T = X * Q^T ; store R[c][j] (transposed) over Q ----
  {
    const int j0b = wr * 64, cb = wc * 128;
    f32x4 acc[4][8];
#pragma unroll
    for (int i = 0; i < 4; ++i)
#pragma unroll
      for (int j = 0; j < 8; ++j) acc[i][j] = (f32x4){0.f, 0.f, 0.f, 0.f};
    for (int k0 = 0; k0 < 256; k0 += 32) {
      bf16x8 a[4];
#pragma unroll
      for (int rt = 0; rt < 4; ++rt) a[rt] = cvt8(xb + (j0b + rt * 16 + lo) * 256 + k0 + hi * 8);
#pragma unroll
      for (int ct = 0; ct < 8; ++ct) {
        bf16x8 bb = *(const bf16x8*)(smem + swz(cb + ct * 16 + lo, (k0 + hi * 8) * 2));
#pragma unroll
        for (int rt = 0; rt < 4; ++rt) acc[rt][ct] = MFMA16(a[rt], bb, acc[rt][ct]);
      }
    }
    __syncthreads();  // all Q reads done before overwrite
#pragma unroll
    for (int rt = 0; rt < 4; ++rt)
#pragma unroll
      for (int ct = 0; ct < 8; ++ct) {
        const int c = cb + ct * 16 + lo;
        const int j0 = j0b + rt * 16 + hi * 4;
        bf16x4 v;
#pragma unroll
        for (int reg = 0; reg < 4; ++reg) v[reg] = (short)f2bf(acc[rt][ct][reg]);
        *(bf16x4*)(smem + swz(c, j0 * 2)) = v;
      }
  }
  __syncthreads();

  // ---- Phase 3: S = R*Wk^T + qsum*bk, scale, softmax rows, write P^T ----
  {
    const int r0 = w * 32;
    f32x4 acc[2][16];
#pragma unroll
    for (int i = 0; i < 2; ++i)
#pragma unroll
      for (int j = 0; j < 16; ++j) acc[i][j] = (f32x4){0.f, 0.f, 0.f, 0.f};
    for (int k0 = 0; k0 < 256; k0 += 32) {
      bf16x8 a[2];
#pragma unroll
      for (int rt = 0; rt < 2; ++rt)
        a[rt] = *(const bf16x8*)(smem + swz(r0 + rt * 16 + lo, (k0 + hi * 8) * 2));
#pragma unroll
      for (int ct = 0; ct < 16; ++ct) {
        bf16x8 bb = cvt8(Wk + (ct * 16 + lo) * 256 + k0 + hi * 8);
#pragma unroll
        for (int rt = 0; rt < 2; ++rt) acc[rt][ct] = MFMA16(a[rt], bb, acc[rt][ct]);
      }
    }
    float bkv[16];
#pragma unroll
    for (int ct = 0; ct < 16; ++ct) bkv[ct] = bk[ct * 16 + lo];
#pragma unroll
    for (int rt = 0; rt < 2; ++rt)
#pragma unroll
      for (int reg = 0; reg < 4; ++reg) {
        const int c = r0 + rt * 16 + hi * 4 + reg;
        const float qs = qsum[c];
        float vals[16];
        float m = -3.0e38f;
#pragma unroll
        for (int ct = 0; ct < 16; ++ct) {
          const float v = (acc[rt][ct][reg] + qs * bkv[ct]) * 0.0625f;
          vals[ct] = v;
          m = fmaxf(m, v);
        }
        m = fmaxf(m, __shfl_xor(m, 1));
        m = fmaxf(m, __shfl_xor(m, 2));
        m = fmaxf(m, __shfl_xor(m, 4));
        m = fmaxf(m, __shfl_xor(m, 8));
        float s = 0.f;
#pragma unroll
        for (int ct = 0; ct < 16; ++ct) {
          const float p = __expf(vals[ct] - m);
          vals[ct] = p;
          s += p;
        }
        s += __shfl_xor(s, 1);
        s += __shfl_xor(s, 2);
        s += __shfl_xor(s, 4);
        s += __shfl_xor(s, 8);
        const float inv = 1.0f / s;
#pragma unroll
        for (int ct = 0; ct < 16; ++ct) acc[rt][ct][reg] = vals[ct] * inv;
      }
    __syncthreads();  // all R reads done before overwrite
#pragma unroll
    for (int rt = 0; rt < 2; ++rt)
#pragma unroll
      for (int ct = 0; ct < 16; ++ct) {
        const int d = ct * 16 + lo;
        const int s0 = r0 + rt * 16 + hi * 4;
        bf16x4 v;
#pragma unroll
        for (int reg = 0; reg < 4; ++reg) v[reg] = (short)f2bf(acc[rt][ct][reg]);
        *(bf16x4*)(smem + swz(d, s0 * 2)) = v;
      }
  }
  __syncthreads();

  // ---- Phase 4: O = V*P ; out = gamma*O + x ----
  {
    const int r0 = wr * 64, d0 = wc * 128;
    f32x4 acc[4][8];
#pragma unroll
    for (int i = 0; i < 4; ++i)
#pragma unroll
      for (int j = 0; j < 8; ++j) acc[i][j] = (f32x4){0.f, 0.f, 0.f, 0.f};
    for (int k0 = 0; k0 < 256; k0 += 32) {
      bf16x8 a[4];
#pragma unroll
      for (int rt = 0; rt < 4; ++rt)
        a[rt] = *(const bf16x8*)(vbp + (r0 + rt * 16 + lo) * 256 + k0 + hi * 8);
#pragma unroll
      for (int ct = 0; ct < 8; ++ct) {
        bf16x8 bb = *(const bf16x8*)(smem + swz(d0 + ct * 16 + lo, (k0 + hi * 8) * 2));
#pragma unroll
        for (int rt = 0; rt < 4; ++rt) acc[rt][ct] = MFMA16(a[rt], bb, acc[rt][ct]);
      }
    }
    const float g = gamma[0];
    float* ob = out + (size_t)b * 65536;
#pragma unroll
    for (int rt = 0; rt < 4; ++rt)
#pragma unroll
      for (int reg = 0; reg < 4; ++reg) {
        const int c = r0 + rt * 16 + hi * 4 + reg;
#pragma unroll
        for (int ct = 0; ct < 8; ++ct) {
          const int d = d0 + ct * 16 + lo;
          const int idx = c * 256 + d;
          ob[idx] = g * acc[rt][ct][reg] + xb[idx];
        }
      }
  }
}

// ---------------------------------------------------------------------------
extern "C" void kernel_launch(void* const* d_in, const int* in_sizes, int n_in,
                              void* d_out, int out_size, void* d_ws, size_t ws_size,
                              hipStream_t stream) {
  const float* x = (const float*)d_in[0];
  const float* Wq = (const float*)d_in[1];
  const float* bq = (const float*)d_in[2];
  const float* Wk = (const float*)d_in[3];
  const float* bk = (const float*)d_in[4];
  const float* Wv = (const float*)d_in[5];
  const float* bv = (const float*)d_in[6];
  const float* gamma = (const float*)d_in[7];
  float* out = (float*)d_out;

  const size_t elems = (size_t)1024 * 65536;
  if (ws_size < elems * 2 * 2) return;  // need 256 MB (Xt + V, bf16)
  unsigned short* Xt = (unsigned short*)d_ws;
  unsigned short* V = Xt + elems;

  hipLaunchKernelGGL(k_transpose, dim3(1024), dim3(256), 0, stream, x, Xt);
  hipLaunchKernelGGL(k_v, dim3(1024), dim3(512), 131072, stream, Wv, bv, Xt, V);
  hipLaunchKernelGGL(attn_fused, dim3(1024), dim3(512), 132096, stream,
                     x, Wq, bq, Wk, bk, gamma, Xt, V, out);
}

// Round 2
// 768.948 us; speedup vs baseline: 1.0577x; 1.0577x over previous
//
#include <hip/hip_runtime.h>

// ---------------------------------------------------------------------------
// SelfAttention: B=1024, C=N=256.  Per batch:
//   Q=(WqX+bq)/16 ; K=WkX+bk ; Vg=gamma*(WvX+bv) ; P=softmax_rows(Q K^T);
//   out = Vg P + x
// Pipeline: cvt weights -> transpose x -> batched QKV projection (chunks of
// 256 batches to fit ws) -> fused attention (S, softmax, O, residual).
// ---------------------------------------------------------------------------

typedef __attribute__((ext_vector_type(8))) short bf16x8;
typedef __attribute__((ext_vector_type(4))) short bf16x4;
typedef __attribute__((ext_vector_type(4))) float f32x4;

#define MFMA16(a, b, c) __builtin_amdgcn_mfma_f32_16x16x32_bf16((a), (b), (c), 0, 0, 0)

static __device__ __forceinline__ unsigned short f2bf(float f) {
  unsigned int u = __float_as_uint(f);
  u += 0x7fffu + ((u >> 16) & 1u);  // round-to-nearest-even
  return (unsigned short)(u >> 16);
}

// 256 rows x 512B swizzled LDS buffer; XOR spreads stride-512B row accesses.
static __device__ __forceinline__ int swz(int row, int byteInRow) {
  return row * 512 + (byteInRow ^ ((row & 7) << 4));
}

// ---------------------------------------------------------------------------
// Kernel 0: f32 -> bf16 weight conversion (once per weight)
// ---------------------------------------------------------------------------
__global__ void k_cvt(const float* __restrict__ in, unsigned short* __restrict__ out) {
  const int i = blockIdx.x * 512 + threadIdx.x;
  out[i] = f2bf(in[i]);
}

// ---------------------------------------------------------------------------
// Kernel 1: Xt[b][n][i] = bf16(x[b][i][n])
// ---------------------------------------------------------------------------
__global__ void k_transpose(const float* __restrict__ x, unsigned short* __restrict__ xt) {
  __shared__ float tile[64][65];
  const int b = blockIdx.x;
  const float* xb = x + (size_t)b * 65536;
  unsigned short* xtb = xt + (size_t)b * 65536;
  const int t = threadIdx.x, tx = t & 63, ty = t >> 6;
  const int cp = t & 31, rb = t >> 5;
  for (int tb = 0; tb < 16; ++tb) {
    const int c0 = (tb >> 2) * 64, n0 = (tb & 3) * 64;
    __syncthreads();
#pragma unroll
    for (int yy = 0; yy < 16; ++yy) {
      const int r = ty + yy * 4;
      tile[r][tx] = xb[(c0 + r) * 256 + n0 + tx];
    }
    __syncthreads();
#pragma unroll
    for (int yy = 0; yy < 8; ++yy) {
      const int nl = rb + yy * 8;
      ushort2 v;
      v.x = f2bf(tile[2 * cp][nl]);
      v.y = f2bf(tile[2 * cp + 1][nl]);
      *(ushort2*)(xtb + (n0 + nl) * 256 + c0 + 2 * cp) = v;
    }
  }
}

// ---------------------------------------------------------------------------
// One projection: dst = (W * X + bias) * sc   (bf16 out, row-major [c][n])
// ---------------------------------------------------------------------------
static __device__ __forceinline__ void proj_one(
    const unsigned short* __restrict__ W, const float* __restrict__ bias, float sc,
    const unsigned short* __restrict__ xtb, unsigned short* __restrict__ dst,
    char* smem, int r0, int c0, int lo, int hi, int tid) {
  f32x4 acc[4][8];
#pragma unroll
  for (int i = 0; i < 4; ++i)
#pragma unroll
    for (int j = 0; j < 8; ++j) acc[i][j] = (f32x4){0.f, 0.f, 0.f, 0.f};
  for (int k0 = 0; k0 < 256; k0 += 32) {
    bf16x8 a[4];
#pragma unroll
    for (int rt = 0; rt < 4; ++rt)
      a[rt] = *(const bf16x8*)(W + (r0 + rt * 16 + lo) * 256 + k0 + hi * 8);
#pragma unroll
    for (int ct = 0; ct < 8; ++ct) {
      bf16x8 bb = *(const bf16x8*)(xtb + (c0 + ct * 16 + lo) * 256 + k0 + hi * 8);
#pragma unroll
      for (int rt = 0; rt < 4; ++rt) acc[rt][ct] = MFMA16(a[rt], bb, acc[rt][ct]);
    }
  }
#pragma unroll
  for (int rt = 0; rt < 4; ++rt)
#pragma unroll
    for (int reg = 0; reg < 4; ++reg) {
      const int c = r0 + rt * 16 + hi * 4 + reg;
      const float bc = bias[c];
#pragma unroll
      for (int ct = 0; ct < 8; ++ct) {
        const int n = c0 + ct * 16 + lo;
        *(unsigned short*)(smem + c * 512 + n * 2) = f2bf((acc[rt][ct][reg] + bc) * sc);
      }
    }
  __syncthreads();
#pragma unroll
  for (int i = 0; i < 16; ++i) {
    const int off = (i * 512 + tid) * 16;
    *(int4*)((char*)dst + off) = *(const int4*)(smem + off);
  }
  __syncthreads();
}

// ---------------------------------------------------------------------------
// Kernel 2: Q/K/V projections for one chunk of batches
// ---------------------------------------------------------------------------
__global__ __launch_bounds__(512, 2) void k_qkv(
    const unsigned short* __restrict__ Wqh, const unsigned short* __restrict__ Wkh,
    const unsigned short* __restrict__ Wvh, const float* __restrict__ bq,
    const float* __restrict__ bk, const float* __restrict__ bv,
    const float* __restrict__ gamma, const unsigned short* __restrict__ xt,
    unsigned short* __restrict__ Qo, unsigned short* __restrict__ Ko,
    unsigned short* __restrict__ Vo) {
  extern __shared__ char smem[];
  const int b = blockIdx.x;
  const unsigned short* xtb = xt + (size_t)b * 65536;
  const int tid = threadIdx.x, w = tid >> 6, lane = tid & 63, lo = lane & 15, hi = lane >> 4;
  const int r0 = (w >> 1) * 64, c0 = (w & 1) * 128;
  const size_t boff = (size_t)b * 65536;
  proj_one(Wqh, bq, 0.0625f, xtb, Qo + boff, smem, r0, c0, lo, hi, tid);
  proj_one(Wkh, bk, 1.0f, xtb, Ko + boff, smem, r0, c0, lo, hi, tid);
  proj_one(Wvh, bv, gamma[0], xtb, Vo + boff, smem, r0, c0, lo, hi, tid);
}

// ---------------------------------------------------------------------------
// Kernel 3: fused attention for one chunk: P = softmax(Q K^T); out = V P + x
// ---------------------------------------------------------------------------
__global__ __launch_bounds__(512, 2) void attn2(
    const float* __restrict__ x, const unsigned short* __restrict__ Q,
    const unsigned short* __restrict__ K, const unsigned short* __restrict__ V,
    float* __restrict__ out) {
  extern __shared__ char smem[];
  const int b = blockIdx.x;
  const float* xb = x + (size_t)b * 65536;
  const unsigned short* Qb = Q + (size_t)b * 65536;
  const unsigned short* Kb = K + (size_t)b * 65536;
  const unsigned short* Vb = V + (size_t)b * 65536;
  const int tid = threadIdx.x, w = tid >> 6, lane = tid & 63, lo = lane & 15, hi = lane >> 4;

  // ---- Stage K into LDS (swizzled rows) ----
#pragma unroll
  for (int i = 0; i < 16; ++i) {
    const int o = i * 8192 + tid * 16;
    const int row = o >> 9, byte = o & 511;
    int4 t = *(const int4*)((const char*)Kb + o);
    *(int4*)(smem + row * 512 + (byte ^ ((row & 7) << 4))) = t;
  }
  __syncthreads();

  // ---- Phase A: S = Q K^T (wave owns 32 rows); softmax; P^T -> LDS ----
  {
    const int r0 = w * 32;
    f32x4 acc[2][16];
#pragma unroll
    for (int i = 0; i < 2; ++i)
#pragma unroll
      for (int j = 0; j < 16; ++j) acc[i][j] = (f32x4){0.f, 0.f, 0.f, 0.f};
    for (int k0 = 0; k0 < 256; k0 += 32) {
      bf16x8 a[2];
#pragma unroll
      for (int rt = 0; rt < 2; ++rt)
        a[rt] = *(const bf16x8*)(Qb + (r0 + rt * 16 + lo) * 256 + k0 + hi * 8);
#pragma unroll
      for (int ct = 0; ct < 16; ++ct) {
        bf16x8 bb = *(const bf16x8*)(smem + swz(ct * 16 + lo, (k0 + hi * 8) * 2));
#pragma unroll
        for (int rt = 0; rt < 2; ++rt) acc[rt][ct] = MFMA16(a[rt], bb, acc[rt][ct]);
      }
    }
    // softmax over each row (16 in-lane cols x 16 lo-lanes)
#pragma unroll
    for (int rt = 0; rt < 2; ++rt)
#pragma unroll
      for (int reg = 0; reg < 4; ++reg) {
        float vals[16];
        float m = -3.0e38f;
#pragma unroll
        for (int ct = 0; ct < 16; ++ct) {
          const float v = acc[rt][ct][reg];
          vals[ct] = v;
          m = fmaxf(m, v);
        }
        m = fmaxf(m, __shfl_xor(m, 1));
        m = fmaxf(m, __shfl_xor(m, 2));
        m = fmaxf(m, __shfl_xor(m, 4));
        m = fmaxf(m, __shfl_xor(m, 8));
        float s = 0.f;
#pragma unroll
        for (int ct = 0; ct < 16; ++ct) {
          const float p = __expf(vals[ct] - m);
          vals[ct] = p;
          s += p;
        }
        s += __shfl_xor(s, 1);
        s += __shfl_xor(s, 2);
        s += __shfl_xor(s, 4);
        s += __shfl_xor(s, 8);
        const float inv = 1.0f / s;
#pragma unroll
        for (int ct = 0; ct < 16; ++ct) acc[rt][ct][reg] = vals[ct] * inv;
      }
    __syncthreads();  // all K reads done before overwrite
#pragma unroll
    for (int rt = 0; rt < 2; ++rt)
#pragma unroll
      for (int ct = 0; ct < 16; ++ct) {
        const int d = ct * 16 + lo;
        const int s0 = r0 + rt * 16 + hi * 4;
        bf16x4 v;
#pragma unroll
        for (int reg = 0; reg < 4; ++reg) v[reg] = (short)f2bf(acc[rt][ct][reg]);
        *(bf16x4*)(smem + swz(d, s0 * 2)) = v;
      }
  }
  __syncthreads();

  // ---- Phase B: O = V P ; out = O + x (gamma already in V) ----
  {
    const int r0 = (w >> 1) * 64, d0 = (w & 1) * 128;
    f32x4 acc[4][8];
#pragma unroll
    for (int i = 0; i < 4; ++i)
#pragma unroll
      for (int j = 0; j < 8; ++j) acc[i][j] = (f32x4){0.f, 0.f, 0.f, 0.f};
    for (int k0 = 0; k0 < 256; k0 += 32) {
      bf16x8 a[4];
#pragma unroll
      for (int rt = 0; rt < 4; ++rt)
        a[rt] = *(const bf16x8*)(Vb + (r0 + rt * 16 + lo) * 256 + k0 + hi * 8);
#pragma unroll
      for (int ct = 0; ct < 8; ++ct) {
        bf16x8 bb = *(const bf16x8*)(smem + swz(d0 + ct * 16 + lo, (k0 + hi * 8) * 2));
#pragma unroll
        for (int rt = 0; rt < 4; ++rt) acc[rt][ct] = MFMA16(a[rt], bb, acc[rt][ct]);
      }
    }
    float* ob = out + (size_t)b * 65536;
#pragma unroll
    for (int rt = 0; rt < 4; ++rt)
#pragma unroll
      for (int reg = 0; reg < 4; ++reg) {
        const int c = r0 + rt * 16 + hi * 4 + reg;
#pragma unroll
        for (int ct = 0; ct < 8; ++ct) {
          const int d = d0 + ct * 16 + lo;
          const int idx = c * 256 + d;
          ob[idx] = acc[rt][ct][reg] + xb[idx];
        }
      }
  }
}

// ---------------------------------------------------------------------------
extern "C" void kernel_launch(void* const* d_in, const int* in_sizes, int n_in,
                              void* d_out, int out_size, void* d_ws, size_t ws_size,
                              hipStream_t stream) {
  const float* x = (const float*)d_in[0];
  const float* Wq = (const float*)d_in[1];
  const float* bq = (const float*)d_in[2];
  const float* Wk = (const float*)d_in[3];
  const float* bk = (const float*)d_in[4];
  const float* Wv = (const float*)d_in[5];
  const float* bv = (const float*)d_in[6];
  const float* gamma = (const float*)d_in[7];
  float* out = (float*)d_out;

  const size_t EB = 65536;                    // elements per batch matrix
  const size_t CHUNK = 256;                   // batches per chunk
  unsigned short* Xt = (unsigned short*)d_ws;          // 1024 batches, 128 MiB
  unsigned short* Qc = Xt + (size_t)1024 * EB;          // 32 MiB
  unsigned short* Kc = Qc + CHUNK * EB;                  // 32 MiB
  unsigned short* Vc = Kc + CHUNK * EB;                  // 32 MiB
  unsigned short* Wqh = Vc + CHUNK * EB;                 // 128 KiB each
  unsigned short* Wkh = Wqh + EB;
  unsigned short* Wvh = Wkh + EB;
  const size_t need = ((size_t)1024 * EB + 3 * CHUNK * EB + 3 * EB) * 2;
  if (ws_size < need) return;  // ~224.4 MiB

  hipLaunchKernelGGL(k_cvt, dim3(128), dim3(512), 0, stream, Wq, Wqh);
  hipLaunchKernelGGL(k_cvt, dim3(128), dim3(512), 0, stream, Wk, Wkh);
  hipLaunchKernelGGL(k_cvt, dim3(128), dim3(512), 0, stream, Wv, Wvh);
  hipLaunchKernelGGL(k_transpose, dim3(1024), dim3(256), 0, stream, x, Xt);

  for (int c = 0; c < 4; ++c) {
    const size_t boff = (size_t)c * CHUNK * EB;
    hipLaunchKernelGGL(k_qkv, dim3(256), dim3(512), 131072, stream,
                       Wqh, Wkh, Wvh, bq, bk, bv, gamma, Xt + boff, Qc, Kc, Vc);
    hipLaunchKernelGGL(attn2, dim3(256), dim3(512), 131072, stream,
                       x + boff, Qc, Kc, Vc, out + boff);
  }
}